// Round 14
// baseline (105.877 us; speedup 1.0000x reference)
//
#include <hip/hip_runtime.h>

#define TPK 512    // K0 block size
#define TPA 1024   // main kernel block size
#define NF0 448    // fill slabs done by K0 (hide wft chain)
#define NACT 256   // active slabs

typedef float f4v __attribute__((ext_vector_type(4)));

// bit-reverse 7 bits
__device__ __forceinline__ int br7(int k) {
  return (int)(__brev((unsigned int)k) >> 25);
}

template <int NT>
__device__ __forceinline__ void zero_fill_slab(float* __restrict__ out,
                                               int zi, int tid) {
  const int zb = zi / 224;
  const int zh = 16 + (zi - zb * 224);
  f4v* o4 = (f4v*)(out + ((size_t)(zb * 256 + zh)) * 32768);
  const f4v z = {0.f, 0.f, 0.f, 0.f};
  #pragma unroll
  for (int i = 0; i < 8192 / NT; ++i)
    __builtin_nontemporal_store(z, &o4[tid + i * NT]);
}

// 16-point in-register radix-2 DIT FFT, sign +. Input bit-reversed, output natural.
__device__ __forceinline__ void fft16_pos(float* ar, float* ai) {
  constexpr float TC[4][8] = {
    {1.f, 0.f, 0.f, 0.f, 0.f, 0.f, 0.f, 0.f},
    {1.f, 0.f, 0.f, 0.f, 0.f, 0.f, 0.f, 0.f},
    {1.f, 0.70710678f, 0.f, -0.70710678f, 0.f, 0.f, 0.f, 0.f},
    {1.f, 0.92387953f, 0.70710678f, 0.38268343f, 0.f, -0.38268343f, -0.70710678f, -0.92387953f}
  };
  constexpr float TS[4][8] = {
    {0.f, 0.f, 0.f, 0.f, 0.f, 0.f, 0.f, 0.f},
    {0.f, 1.f, 0.f, 0.f, 0.f, 0.f, 0.f, 0.f},
    {0.f, 0.70710678f, 1.f, 0.70710678f, 0.f, 0.f, 0.f, 0.f},
    {0.f, 0.38268343f, 0.70710678f, 0.92387953f, 1.f, 0.92387953f, 0.70710678f, 0.38268343f}
  };
  #pragma unroll
  for (int s = 0; s < 4; ++s) {
    const int L = 1 << s;
    #pragma unroll
    for (int jj = 0; jj < 8; ++jj) {
      if (jj < L) {
        const float tc = TC[s][jj], ts = TS[s][jj];
        #pragma unroll
        for (int i0 = jj; i0 < 16; i0 += 2 * L) {
          const float xr = ar[i0 + L], xi = ai[i0 + L];
          const float pr = xr * tc - xi * ts;
          const float pi = xr * ts + xi * tc;
          const float qr = ar[i0], qi = ai[i0];
          ar[i0 + L] = qr - pr; ai[i0 + L] = qi - pi;
          ar[i0]     = qr + pr; ai[i0]     = qi + pi;
        }
      }
    }
  }
}

// Phase A: W-direction partial DFT + cross-group reduction.
// Register-lean g-interleaved form: each DFT-16 bin (sr,si) is immediately
// twiddle-accumulated into f=g (direct) and f=16-g (conjugate) — no SRe/SIm
// arrays. Result: XR/XI[f][c] natural-c, f=0..16. SR/SI: [17][128] scratch.
template <int TPBv>
__device__ void phaseA_reduce(const float* __restrict__ src,
                              float (*XR)[128], float (*XI)[128],
                              float (*SR)[128], float (*SI)[128],
                              const float* Rc, const float* Rs, int tid) {
  constexpr int NQ = TPBv / 128;
  constexpr int JN = 16 / NQ;
  const int c = tid & 127;
  const int q = tid >> 7;

  constexpr float C16[16] = {1.f, 0.92387953f, 0.70710678f, 0.38268343f, 0.f,
                             -0.38268343f, -0.70710678f, -0.92387953f, -1.f,
                             -0.92387953f, -0.70710678f, -0.38268343f, 0.f,
                             0.38268343f, 0.70710678f, 0.92387953f};
  constexpr float S16[16] = {0.f, 0.38268343f, 0.70710678f, 0.92387953f, 1.f,
                             0.92387953f, 0.70710678f, 0.38268343f, 0.f,
                             -0.38268343f, -0.70710678f, -0.92387953f, -1.f,
                             -0.92387953f, -0.70710678f, -0.38268343f};

  float accR[17], accI[17];
  #pragma unroll
  for (int f = 0; f < 17; ++f) { accR[f] = 0.f; accI[f] = 0.f; }

  #pragma unroll 2
  for (int j = 0; j < JN; ++j) {
    const int w0 = q * JN + j;
    float xv[16];
    #pragma unroll
    for (int w1 = 0; w1 < 16; ++w1)
      xv[w1] = src[(w1 * 16 + w0) * 128 + c];
    #pragma unroll
    for (int g = 0; g <= 8; ++g) {
      float sr = 0.f, si = 0.f;
      #pragma unroll
      for (int w1 = 0; w1 < 16; ++w1) {
        const int m = (g * w1) & 15;
        sr = fmaf(xv[w1], C16[m], sr);
        si = fmaf(xv[w1], -S16[m], si);
      }
      { // direct: f = g
        const int idx = (g * w0) & 255;
        const float rc = Rc[idx], rs = Rs[idx];
        accR[g] = fmaf(sr, rc, fmaf(si, rs, accR[g]));
        accI[g] = fmaf(si, rc, fmaf(-sr, rs, accI[g]));
      }
      if (g == 0) { // f = 16, direct (f&15 = 0)
        const int idx = (16 * w0) & 255;
        const float rc = Rc[idx], rs = Rs[idx];
        accR[16] = fmaf(sr, rc, fmaf(si, rs, accR[16]));
        accI[16] = fmaf(si, rc, fmaf(-sr, rs, accI[16]));
      } else if (g <= 7) { // conj: f2 = 16-g (f2&15 > 8 -> conj S[g])
        const int f2 = 16 - g;
        const int idx = (f2 * w0) & 255;
        const float rc = Rc[idx], rs = Rs[idx];
        accR[f2] = fmaf(sr, rc, fmaf(-si, rs, accR[f2]));
        accI[f2] = fmaf(-si, rc, fmaf(-sr, rs, accI[f2]));
      }
    }
  }
  #pragma unroll
  for (int r = 0; r < NQ / 2; ++r) {
    if (q == 2 * r) {
      if (r == 0) {
        #pragma unroll
        for (int f = 0; f < 17; ++f) { XR[f][c] = accR[f]; XI[f][c] = accI[f]; }
      } else {
        #pragma unroll
        for (int f = 0; f < 17; ++f) { XR[f][c] += accR[f]; XI[f][c] += accI[f]; }
      }
    } else if (q == 2 * r + 1) {
      if (r == 0) {
        #pragma unroll
        for (int f = 0; f < 17; ++f) { SR[f][c] = accR[f]; SI[f][c] = accI[f]; }
      } else {
        #pragma unroll
        for (int f = 0; f < 17; ++f) { SR[f][c] += accR[f]; SI[f][c] += accI[f]; }
      }
    }
    __syncthreads();
  }
  for (int u = tid; u < 17 * 128; u += TPBv) {
    const int row = u >> 7, cc = u & 127;
    XR[row][cc] += SR[row][cc];
    XI[row][cc] += SI[row][cc];
  }
  __syncthreads();
}

// 128-pt LDS DIF FFT (sign -, natural in -> bit-reversed out), 17 rows.
template <int TPBv>
__device__ void fftc17_lds(float (*XR)[128], float (*XI)[128],
                           const float* Rc, const float* Rs, int tid) {
  for (int s = 6; s >= 0; --s) {
    const int L = 1 << s;
    for (int u = tid; u < 17 * 64; u += TPBv) {
      const int row = u >> 6, qq = u & 63;
      const int jj = qq & (L - 1);
      const int pos = ((qq >> s) << (s + 1)) | jj;
      const int ti = jj << (7 - s);
      const float tc = Rc[ti], ts = Rs[ti];
      const float a0r = XR[row][pos],     a0i = XI[row][pos];
      const float b0r = XR[row][pos + L], b0i = XI[row][pos + L];
      XR[row][pos] = a0r + b0r; XI[row][pos] = a0i + b0i;
      const float dr = a0r - b0r, di = a0i - b0i;
      XR[row][pos + L] = fmaf(dr, tc, di * ts);
      XI[row][pos + L] = fmaf(di, tc, -dr * ts);
    }
    __syncthreads();
  }
}

// K0: blocks 0..63 precompute w_ft/b_ft spectra; blocks 64.. fill the first
// NF0 inactive slabs (soaks the idle CUs under the wft latency chain).
__global__ __launch_bounds__(TPK) void k0_wft_and_fill(
    const float* __restrict__ wp, const float* __restrict__ bp,
    float2* __restrict__ wsW, float2* __restrict__ wsB,
    float* __restrict__ out) {
  const int bid = blockIdx.x;
  const int tid = threadIdx.x;
  if (bid >= 64) {
    zero_fill_slab<TPK>(out, bid - 64, tid);
    return;
  }
  __shared__ float XR[17][128], XI[17][128];
  __shared__ float SR[17][128], SI[17][128];
  __shared__ float Rc[256], Rs[256];
  for (int i = tid; i < 256; i += TPK) {
    float sv, cv; sincosf(6.283185307179586f * (float)i / 256.0f, &sv, &cv);
    Rc[i] = cv; Rs[i] = sv;
  }
  __syncthreads();
  const int which = bid >> 5;   // 0 = w, 1 = b
  const int ha = bid & 31;
  const int h = (ha < 16) ? ha : (224 + ha);
  const float* src = (which ? bp : wp) + (size_t)h * 32768;
  phaseA_reduce<TPK>(src, XR, XI, SR, SI, Rc, Rs, tid);
  fftc17_lds<TPK>(XR, XI, Rc, Rs, tid);
  float2* dst = which ? wsB : wsW;
  for (int u = tid; u < 32 * 65; u += TPK) {
    const int fi = u / 65, k = u - fi * 65;
    const int f = fi - 16;
    float xr, xi;
    if (f >= 0) { const int p = br7(k); xr = XR[f][p]; xi = XI[f][p]; }
    else { const int kk = (128 - k) & 127; const int p = br7(kk);
           xr = XR[-f][p]; xi = -XI[-f][p]; }
    dst[(ha * 32 + fi) * 65 + k] = make_float2(xr, xi);
  }
}

// Main kernel: blocks 0..255 = active slab pipeline (16 waves); blocks 256..
// = fill slabs. __launch_bounds__(1024, 8) forces VGPR <= 64 so ONE active
// block + ONE fill block co-reside per CU (32 waves, LDS 2x51KB <= 160KB):
// fill blocks stream HBM writes from their own waves while the active
// block's latency chain runs -> true overlap (R10/R13's embedded stores
// could not do this: no compute window inside a single wave's chain).
__global__ __launch_bounds__(TPA, 8) void fourier_main(
    const float* __restrict__ x, const float2* __restrict__ wsW,
    const float2* __restrict__ wsB, float* __restrict__ out) {
  const int bid = blockIdx.x;
  const int tid = threadIdx.x;
  if (bid >= NACT) {
    zero_fill_slab<TPA>(out, NF0 + (bid - NACT), tid);
    return;
  }
  __shared__ float XR[17][128], XI[17][128];
  __shared__ float TR[32][128], TI[32][128];
  __shared__ float Rc[256], Rs[256];
  for (int i = tid; i < 256; i += TPA) {
    float sv, cv; sincosf(6.283185307179586f * (float)i / 256.0f, &sv, &cv);
    Rc[i] = cv; Rs[i] = sv;
  }
  __syncthreads();

  const int b = bid >> 5;
  const int ha = bid & 31;
  const int h = (ha < 16) ? ha : (224 + ha);
  const float* src = x + ((size_t)(b * 256 + h)) * 32768;
  // TR/TI rows 0..16 double as the phase-A reduction scratch.
  phaseA_reduce<TPA>(src, XR, XI, (float(*)[128])TR, (float(*)[128])TI,
                     Rc, Rs, tid);

  // forward 128-pt c-FFT, 17 rows (natural -> bit-reversed)
  fftc17_lds<TPA>(XR, XI, Rc, Rs, tid);

  // phase C: Z = X*Wft + Bft, alpha weights, zero k>64, bit-reversed into TR/TI.
  for (int u = tid; u < 32 * 128; u += TPA) {
    const int fi = u >> 7, k = u & 127;
    float gr = 0.f, gi = 0.f;
    if (k <= 64) {
      const int f = fi - 16;
      float xr, xi;
      if (f >= 0) { const int p = br7(k); xr = XR[f][p]; xi = XI[f][p]; }
      else { const int kk = (128 - k) & 127; const int p = br7(kk);
             xr = XR[-f][p]; xi = -XI[-f][p]; }
      const float2 wf = wsW[(ha * 32 + fi) * 65 + k];
      const float2 bf = wsB[(ha * 32 + fi) * 65 + k];
      gr = xr * wf.x - xi * wf.y + bf.x;
      gi = xr * wf.y + xi * wf.x + bf.y;
      const float al = (k == 0 || k == 64) ? 1.f : 2.f;
      gr *= al; gi *= al;
    }
    const int p = br7(k);
    TR[fi][p] = gr; TI[fi][p] = gi;
  }
  __syncthreads();

  // phase D: inverse 128-pt DIT (sign +), 32 rows, bitrev-in natural-out.
  for (int s = 0; s <= 6; ++s) {
    const int L = 1 << s;
    for (int u = tid; u < 32 * 64; u += TPA) {
      const int row = u >> 6, qq = u & 63;
      const int jj = qq & (L - 1);
      const int pos = ((qq >> s) << (s + 1)) | jj;
      const int ti = jj << (7 - s);
      const float tc = Rc[ti], ts = Rs[ti];
      const float b0r = TR[row][pos + L], b0i = TI[row][pos + L];
      const float pr = b0r * tc - b0i * ts;
      const float pi = fmaf(b0r, ts, b0i * tc);
      const float a0r = TR[row][pos], a0i = TI[row][pos];
      TR[row][pos + L] = a0r - pr; TI[row][pos + L] = a0i - pi;
      TR[row][pos]     = a0r + pr; TI[row][pos]     = a0i + pi;
    }
    __syncthreads();
  }

  // phase E: out[16*w1+w0, c] = (1/32768) * Re( sum_g U[g] e^{+2pi i g w1/16} )
  const int c = tid & 127;
  const int q = tid >> 7;          // 0..7
  constexpr int BR4[16] = {0, 8, 4, 12, 2, 10, 6, 14, 1, 9, 5, 13, 3, 11, 7, 15};
  const float inv = 1.0f / 32768.0f;
  float* og = out + ((size_t)(b * 256 + h)) * 32768;

  #pragma unroll 1
  for (int it = 0; it < 2; ++it) {
    const int w0 = q + it * 8;     // wave-uniform
    float Ur[16], Ui[16];
    #pragma unroll
    for (int g = 0; g < 16; ++g) {
      const int gb = BR4[g];
      const float t1r = TR[gb + 16][c], t1i = TI[gb + 16][c];
      const float t0r = TR[gb][c],      t0i = TI[gb][c];
      const int iw1 = (gb * w0) & 255;
      const int iw2 = ((gb - 16) * w0) & 255;
      const float c1 = Rc[iw1], s1 = Rs[iw1];
      const float c2 = Rc[iw2], s2 = Rs[iw2];
      Ur[g] = t1r * c1 - t1i * s1 + t0r * c2 - t0i * s2;
      Ui[g] = t1r * s1 + t1i * c1 + t0r * s2 + t0i * c2;
    }
    fft16_pos(Ur, Ui);
    #pragma unroll
    for (int w1 = 0; w1 < 16; ++w1)
      og[(w1 * 16 + w0) * 128 + c] = Ur[w1] * inv;
  }
}

extern "C" void kernel_launch(void* const* d_in, const int* in_sizes, int n_in,
                              void* d_out, int out_size, void* d_ws, size_t ws_size,
                              hipStream_t stream) {
  const float* x = (const float*)d_in[0];
  const float* w = (const float*)d_in[1];
  const float* b = (const float*)d_in[2];
  float* out = (float*)d_out;
  float2* wsW = (float2*)d_ws;
  float2* wsB = wsW + 32 * 32 * 65;   // 66560 float2 each (532,480 B)

  hipLaunchKernelGGL(k0_wft_and_fill, dim3(64 + NF0), dim3(TPK), 0, stream,
                     w, b, wsW, wsB, out);
  hipLaunchKernelGGL(fourier_main, dim3(NACT + (1792 - NF0)), dim3(TPA), 0,
                     stream, x, wsW, wsB, out);
}

// Round 15
// 70.561 us; speedup vs baseline: 1.5005x; 1.5005x over previous
//
#include <hip/hip_runtime.h>

#define TPK 512    // K0 block size
#define TPA 1024   // main kernel block size
#define CTH 768    // compute threads per main block (12 waves)
#define FPB 6      // fill slabs per active block (256*6 = 1536)
#define NF0 256    // fill slabs done by K0 (1536 + 256 = 1792)
#define NACT 256
#define NBAR 19    // matched barrier count after the shared trig barrier

typedef float f4v __attribute__((ext_vector_type(4)));

// bit-reverse 7 bits
__device__ __forceinline__ int br7(int k) {
  return (int)(__brev((unsigned int)k) >> 25);
}

// Barrier waiting LDS ops ONLY (opaque asm: waitcnt pass can't add vmcnt(0)).
// NT fill stores stay in flight across it.
__device__ __forceinline__ void bar_lds() {
  asm volatile("s_waitcnt lgkmcnt(0)\ns_barrier" ::: "memory");
}

template <int NT>
__device__ __forceinline__ void zero_fill_slab(float* __restrict__ out,
                                               int zi, int tid) {
  const int zb = zi / 224;
  const int zh = 16 + (zi - zb * 224);
  f4v* o4 = (f4v*)(out + ((size_t)(zb * 256 + zh)) * 32768);
  const f4v z = {0.f, 0.f, 0.f, 0.f};
  #pragma unroll
  for (int i = 0; i < 8192 / NT; ++i)
    __builtin_nontemporal_store(z, &o4[tid + i * NT]);
}

// 16-point in-register radix-2 DIT FFT, sign +. Input bit-reversed, output natural.
__device__ __forceinline__ void fft16_pos(float* ar, float* ai) {
  constexpr float TC[4][8] = {
    {1.f, 0.f, 0.f, 0.f, 0.f, 0.f, 0.f, 0.f},
    {1.f, 0.f, 0.f, 0.f, 0.f, 0.f, 0.f, 0.f},
    {1.f, 0.70710678f, 0.f, -0.70710678f, 0.f, 0.f, 0.f, 0.f},
    {1.f, 0.92387953f, 0.70710678f, 0.38268343f, 0.f, -0.38268343f, -0.70710678f, -0.92387953f}
  };
  constexpr float TS[4][8] = {
    {0.f, 0.f, 0.f, 0.f, 0.f, 0.f, 0.f, 0.f},
    {0.f, 1.f, 0.f, 0.f, 0.f, 0.f, 0.f, 0.f},
    {0.f, 0.70710678f, 1.f, 0.70710678f, 0.f, 0.f, 0.f, 0.f},
    {0.f, 0.38268343f, 0.70710678f, 0.92387953f, 1.f, 0.92387953f, 0.70710678f, 0.38268343f}
  };
  #pragma unroll
  for (int s = 0; s < 4; ++s) {
    const int L = 1 << s;
    #pragma unroll
    for (int jj = 0; jj < 8; ++jj) {
      if (jj < L) {
        const float tc = TC[s][jj], ts = TS[s][jj];
        #pragma unroll
        for (int i0 = jj; i0 < 16; i0 += 2 * L) {
          const float xr = ar[i0 + L], xi = ai[i0 + L];
          const float pr = xr * tc - xi * ts;
          const float pi = xr * ts + xi * tc;
          const float qr = ar[i0], qi = ai[i0];
          ar[i0 + L] = qr - pr; ai[i0 + L] = qi - pi;
          ar[i0]     = qr + pr; ai[i0]     = qi + pi;
        }
      }
    }
  }
}

// R13-proven phase A (SRe/SIm form) for K0 at TPBv=512.
template <int TPBv>
__device__ void phaseA_reduce(const float* __restrict__ src,
                              float (*XR)[128], float (*XI)[128],
                              float (*SR)[128], float (*SI)[128],
                              const float* Rc, const float* Rs, int tid) {
  constexpr int NQ = TPBv / 128;
  constexpr int JN = 16 / NQ;
  const int c = tid & 127;
  const int q = tid >> 7;

  constexpr float C16[16] = {1.f, 0.92387953f, 0.70710678f, 0.38268343f, 0.f,
                             -0.38268343f, -0.70710678f, -0.92387953f, -1.f,
                             -0.92387953f, -0.70710678f, -0.38268343f, 0.f,
                             0.38268343f, 0.70710678f, 0.92387953f};
  constexpr float S16[16] = {0.f, 0.38268343f, 0.70710678f, 0.92387953f, 1.f,
                             0.92387953f, 0.70710678f, 0.38268343f, 0.f,
                             -0.38268343f, -0.70710678f, -0.92387953f, -1.f,
                             -0.92387953f, -0.70710678f, -0.38268343f};

  float accR[17], accI[17];
  #pragma unroll
  for (int f = 0; f < 17; ++f) { accR[f] = 0.f; accI[f] = 0.f; }

  #pragma unroll
  for (int j = 0; j < JN; ++j) {
    const int w0 = q * JN + j;
    float xv[16];
    #pragma unroll
    for (int w1 = 0; w1 < 16; ++w1)
      xv[w1] = src[(w1 * 16 + w0) * 128 + c];
    float SRe[9], SIm[9];
    #pragma unroll
    for (int g = 0; g < 9; ++g) {
      float sr = 0.f, si = 0.f;
      #pragma unroll
      for (int w1 = 0; w1 < 16; ++w1) {
        const int m = (g * w1) & 15;
        sr = fmaf(xv[w1], C16[m], sr);
        si = fmaf(xv[w1], -S16[m], si);
      }
      SRe[g] = sr; SIm[g] = si;
    }
    #pragma unroll
    for (int f = 0; f < 17; ++f) {
      const int g = f & 15;
      const float sr = (g <= 8) ? SRe[g] : SRe[16 - g];
      const float si = (g <= 8) ? SIm[g] : -SIm[16 - g];
      const int idx = (f * w0) & 255;
      const float tc = Rc[idx], ts = -Rs[idx];
      accR[f] = fmaf(sr, tc, fmaf(-si, ts, accR[f]));
      accI[f] = fmaf(sr, ts, fmaf(si, tc, accI[f]));
    }
  }
  #pragma unroll
  for (int r = 0; r < NQ / 2; ++r) {
    if (q == 2 * r) {
      if (r == 0) {
        #pragma unroll
        for (int f = 0; f < 17; ++f) { XR[f][c] = accR[f]; XI[f][c] = accI[f]; }
      } else {
        #pragma unroll
        for (int f = 0; f < 17; ++f) { XR[f][c] += accR[f]; XI[f][c] += accI[f]; }
      }
    } else if (q == 2 * r + 1) {
      if (r == 0) {
        #pragma unroll
        for (int f = 0; f < 17; ++f) { SR[f][c] = accR[f]; SI[f][c] = accI[f]; }
      } else {
        #pragma unroll
        for (int f = 0; f < 17; ++f) { SR[f][c] += accR[f]; SI[f][c] += accI[f]; }
      }
    }
    __syncthreads();
  }
  for (int u = tid; u < 17 * 128; u += TPBv) {
    const int row = u >> 7, cc = u & 127;
    XR[row][cc] += SR[row][cc];
    XI[row][cc] += SI[row][cc];
  }
  __syncthreads();
}

// 128-pt LDS DIF FFT (sign -, natural -> bit-reversed), 17 rows (K0 path).
template <int TPBv>
__device__ void fftc17_lds(float (*XR)[128], float (*XI)[128],
                           const float* Rc, const float* Rs, int tid) {
  for (int s = 6; s >= 0; --s) {
    const int L = 1 << s;
    for (int u = tid; u < 17 * 64; u += TPBv) {
      const int row = u >> 6, qq = u & 63;
      const int jj = qq & (L - 1);
      const int pos = ((qq >> s) << (s + 1)) | jj;
      const int ti = jj << (7 - s);
      const float tc = Rc[ti], ts = Rs[ti];
      const float a0r = XR[row][pos],     a0i = XI[row][pos];
      const float b0r = XR[row][pos + L], b0i = XI[row][pos + L];
      XR[row][pos] = a0r + b0r; XI[row][pos] = a0i + b0i;
      const float dr = a0r - b0r, di = a0i - b0i;
      XR[row][pos + L] = fmaf(dr, tc, di * ts);
      XI[row][pos + L] = fmaf(di, tc, -dr * ts);
    }
    __syncthreads();
  }
}

// K0: blocks 0..63 precompute w_ft/b_ft; blocks 64.. fill first NF0 slabs.
__global__ __launch_bounds__(TPK) void k0_wft_and_fill(
    const float* __restrict__ wp, const float* __restrict__ bp,
    float2* __restrict__ wsW, float2* __restrict__ wsB,
    float* __restrict__ out) {
  const int bid = blockIdx.x;
  const int tid = threadIdx.x;
  if (bid >= 64) {
    zero_fill_slab<TPK>(out, bid - 64, tid);
    return;
  }
  __shared__ float XR[17][128], XI[17][128];
  __shared__ float SR[17][128], SI[17][128];
  __shared__ float Rc[256], Rs[256];
  for (int i = tid; i < 256; i += TPK) {
    float sv, cv; sincosf(6.283185307179586f * (float)i / 256.0f, &sv, &cv);
    Rc[i] = cv; Rs[i] = sv;
  }
  __syncthreads();
  const int which = bid >> 5;   // 0 = w, 1 = b
  const int ha = bid & 31;
  const int h = (ha < 16) ? ha : (224 + ha);
  const float* src = (which ? bp : wp) + (size_t)h * 32768;
  phaseA_reduce<TPK>(src, XR, XI, SR, SI, Rc, Rs, tid);
  fftc17_lds<TPK>(XR, XI, Rc, Rs, tid);
  float2* dst = which ? wsB : wsW;
  for (int u = tid; u < 32 * 65; u += TPK) {
    const int fi = u / 65, k = u - fi * 65;
    const int f = fi - 16;
    float xr, xi;
    if (f >= 0) { const int p = br7(k); xr = XR[f][p]; xi = XI[f][p]; }
    else { const int kk = (128 - k) & 127; const int p = br7(kk);
           xr = XR[-f][p]; xi = -XI[-f][p]; }
    dst[(ha * 32 + fi) * 65 + k] = make_float2(xr, xi);
  }
}

// Main kernel: 256 blocks of 1024 threads. Waves 0-11 (tid<768) run the
// active slab pipeline; waves 12-15 stream FPB slabs of NT zero-stores.
// Fill-wave issue stalls are free: the SIMD scheduler picks compute waves
// (this is what R13's same-wave embedded stores could NOT achieve).
// BOTH paths execute exactly NBAR matched bar_lds after the shared barrier.
__global__ __launch_bounds__(TPA) void fourier_main(
    const float* __restrict__ x, const float2* __restrict__ wsW,
    const float2* __restrict__ wsB, float* __restrict__ out) {
  const int bid = blockIdx.x;
  const int tid = threadIdx.x;
  __shared__ float XR[17][128], XI[17][128];
  __shared__ float TR[32][128], TI[32][128];
  __shared__ float Rc[256], Rs[256];
  for (int i = tid; i < 256; i += TPA) {
    float sv, cv; sincosf(6.283185307179586f * (float)i / 256.0f, &sv, &cv);
    Rc[i] = cv; Rs[i] = sv;
  }
  bar_lds();                                   // shared barrier #0

  if (tid >= CTH) {
    // ---- fill waves: 256 threads, 192 NT stores each (6 slabs) ----
    const int ftid = tid - CTH;
    const f4v z = {0.f, 0.f, 0.f, 0.f};
    #pragma unroll 1
    for (int p = 0; p < NBAR; ++p) {
      #pragma unroll
      for (int j = 0; j < 11; ++j) {
        const int idx = p * 11 + j;            // 19*11 = 209 >= 192
        if (idx < FPB * 32) {
          const int s = idx >> 5;              // slab 0..5
          const int zi = NF0 + bid * FPB + s;
          const int zb = zi / 224;
          const int zh = 16 + (zi - zb * 224);
          f4v* o4 = (f4v*)(out + ((size_t)(zb * 256 + zh)) * 32768);
          __builtin_nontemporal_store(z, &o4[((idx & 31) << 8) + ftid]);
        }
      }
      bar_lds();                               // matched barriers 1..NBAR
    }
    return;                                    // no barriers remain below
  }

  // ---- compute waves: 768 threads ----
  const int c = tid & 127;
  const int q = tid >> 7;                      // 0..5 (wave-uniform)
  const int b = bid >> 5;
  const int ha = bid & 31;
  const int h = (ha < 16) ? ha : (224 + ha);
  const float* src = x + ((size_t)(b * 256 + h)) * 32768;

  // phase A: uneven w0 split — q<4: 3 w0 (0..11); q=4,5: 2 w0 (12..15).
  {
    constexpr float C16[16] = {1.f, 0.92387953f, 0.70710678f, 0.38268343f, 0.f,
                               -0.38268343f, -0.70710678f, -0.92387953f, -1.f,
                               -0.92387953f, -0.70710678f, -0.38268343f, 0.f,
                               0.38268343f, 0.70710678f, 0.92387953f};
    constexpr float S16[16] = {0.f, 0.38268343f, 0.70710678f, 0.92387953f, 1.f,
                               0.92387953f, 0.70710678f, 0.38268343f, 0.f,
                               -0.38268343f, -0.70710678f, -0.92387953f, -1.f,
                               -0.92387953f, -0.70710678f, -0.38268343f};
    const int jn = (q < 4) ? 3 : 2;
    const int w0base = (q < 4) ? 3 * q : 12 + 2 * (q - 4);
    float accR[17], accI[17];
    #pragma unroll
    for (int f = 0; f < 17; ++f) { accR[f] = 0.f; accI[f] = 0.f; }
    #pragma unroll
    for (int j = 0; j < 3; ++j) {
      if (j < jn) {                            // wave-uniform guard
        const int w0 = w0base + j;
        float xv[16];
        #pragma unroll
        for (int w1 = 0; w1 < 16; ++w1)
          xv[w1] = src[(w1 * 16 + w0) * 128 + c];
        float SRe[9], SIm[9];
        #pragma unroll
        for (int g = 0; g < 9; ++g) {
          float sr = 0.f, si = 0.f;
          #pragma unroll
          for (int w1 = 0; w1 < 16; ++w1) {
            const int m = (g * w1) & 15;
            sr = fmaf(xv[w1], C16[m], sr);
            si = fmaf(xv[w1], -S16[m], si);
          }
          SRe[g] = sr; SIm[g] = si;
        }
        #pragma unroll
        for (int f = 0; f < 17; ++f) {
          const int g = f & 15;
          const float sr = (g <= 8) ? SRe[g] : SRe[16 - g];
          const float si = (g <= 8) ? SIm[g] : -SIm[16 - g];
          const int idx = (f * w0) & 255;
          const float tc = Rc[idx], ts = -Rs[idx];
          accR[f] = fmaf(sr, tc, fmaf(-si, ts, accR[f]));
          accI[f] = fmaf(sr, ts, fmaf(si, tc, accI[f]));
        }
      }
    }
    // 6-way reduction: 3 paired rounds + merge = 4 barriers.
    float (*SR)[128] = (float(*)[128])TR;
    float (*SI)[128] = (float(*)[128])TI;
    if (q == 0) {
      #pragma unroll
      for (int f = 0; f < 17; ++f) { XR[f][c] = accR[f]; XI[f][c] = accI[f]; }
    } else if (q == 1) {
      #pragma unroll
      for (int f = 0; f < 17; ++f) { SR[f][c] = accR[f]; SI[f][c] = accI[f]; }
    }
    bar_lds();                                 // 1
    if (q == 2) {
      #pragma unroll
      for (int f = 0; f < 17; ++f) { XR[f][c] += accR[f]; XI[f][c] += accI[f]; }
    } else if (q == 3) {
      #pragma unroll
      for (int f = 0; f < 17; ++f) { SR[f][c] += accR[f]; SI[f][c] += accI[f]; }
    }
    bar_lds();                                 // 2
    if (q == 4) {
      #pragma unroll
      for (int f = 0; f < 17; ++f) { XR[f][c] += accR[f]; XI[f][c] += accI[f]; }
    } else if (q == 5) {
      #pragma unroll
      for (int f = 0; f < 17; ++f) { SR[f][c] += accR[f]; SI[f][c] += accI[f]; }
    }
    bar_lds();                                 // 3
    for (int u = tid; u < 17 * 128; u += CTH) {
      const int row = u >> 7, cc = u & 127;
      XR[row][cc] += SR[row][cc];
      XI[row][cc] += SI[row][cc];
    }
    bar_lds();                                 // 4
  }

  // fwd 128-pt DIF FFT (sign -), 17 rows: 7 barriers (5..11).
  for (int s = 6; s >= 0; --s) {
    const int L = 1 << s;
    for (int u = tid; u < 17 * 64; u += CTH) {
      const int row = u >> 6, qq = u & 63;
      const int jj = qq & (L - 1);
      const int pos = ((qq >> s) << (s + 1)) | jj;
      const int ti = jj << (7 - s);
      const float tc = Rc[ti], ts = Rs[ti];
      const float a0r = XR[row][pos],     a0i = XI[row][pos];
      const float b0r = XR[row][pos + L], b0i = XI[row][pos + L];
      XR[row][pos] = a0r + b0r; XI[row][pos] = a0i + b0i;
      const float dr = a0r - b0r, di = a0i - b0i;
      XR[row][pos + L] = fmaf(dr, tc, di * ts);
      XI[row][pos + L] = fmaf(di, tc, -dr * ts);
    }
    bar_lds();
  }

  // phase C: pointwise + alpha, bit-reversed into TR/TI: 1 barrier (12).
  for (int u = tid; u < 32 * 128; u += CTH) {
    const int fi = u >> 7, k = u & 127;
    float gr = 0.f, gi = 0.f;
    if (k <= 64) {
      const int f = fi - 16;
      float xr, xi;
      if (f >= 0) { const int p = br7(k); xr = XR[f][p]; xi = XI[f][p]; }
      else { const int kk = (128 - k) & 127; const int p = br7(kk);
             xr = XR[-f][p]; xi = -XI[-f][p]; }
      const float2 wf = wsW[(ha * 32 + fi) * 65 + k];
      const float2 bf = wsB[(ha * 32 + fi) * 65 + k];
      gr = xr * wf.x - xi * wf.y + bf.x;
      gi = xr * wf.y + xi * wf.x + bf.y;
      const float al = (k == 0 || k == 64) ? 1.f : 2.f;
      gr *= al; gi *= al;
    }
    const int p = br7(k);
    TR[fi][p] = gr; TI[fi][p] = gi;
  }
  bar_lds();

  // phase D: inverse 128-pt DIT (sign +), 32 rows: 7 barriers (13..19).
  for (int s = 0; s <= 6; ++s) {
    const int L = 1 << s;
    for (int u = tid; u < 32 * 64; u += CTH) {
      const int row = u >> 6, qq = u & 63;
      const int jj = qq & (L - 1);
      const int pos = ((qq >> s) << (s + 1)) | jj;
      const int ti = jj << (7 - s);
      const float tc = Rc[ti], ts = Rs[ti];
      const float b0r = TR[row][pos + L], b0i = TI[row][pos + L];
      const float pr = b0r * tc - b0i * ts;
      const float pi = fmaf(b0r, ts, b0i * tc);
      const float a0r = TR[row][pos], a0i = TI[row][pos];
      TR[row][pos + L] = a0r - pr; TI[row][pos + L] = a0i - pi;
      TR[row][pos]     = a0r + pr; TI[row][pos]     = a0i + pi;
    }
    bar_lds();
  }

  // phase E (no barriers): w0 = q + 6*it, it = 0..2, skip w0 >= 16.
  constexpr int BR4[16] = {0, 8, 4, 12, 2, 10, 6, 14, 1, 9, 5, 13, 3, 11, 7, 15};
  const float inv = 1.0f / 32768.0f;
  float* og = out + ((size_t)(b * 256 + h)) * 32768;

  #pragma unroll 1
  for (int it = 0; it < 3; ++it) {
    const int w0 = q + 6 * it;                 // wave-uniform
    if (w0 < 16) {
      float Ur[16], Ui[16];
      #pragma unroll
      for (int g = 0; g < 16; ++g) {
        const int gb = BR4[g];
        const float t1r = TR[gb + 16][c], t1i = TI[gb + 16][c];
        const float t0r = TR[gb][c],      t0i = TI[gb][c];
        const int iw1 = (gb * w0) & 255;
        const int iw2 = ((gb - 16) * w0) & 255;
        const float c1 = Rc[iw1], s1 = Rs[iw1];
        const float c2 = Rc[iw2], s2 = Rs[iw2];
        Ur[g] = t1r * c1 - t1i * s1 + t0r * c2 - t0i * s2;
        Ui[g] = t1r * s1 + t1i * c1 + t0r * s2 + t0i * c2;
      }
      fft16_pos(Ur, Ui);
      #pragma unroll
      for (int w1 = 0; w1 < 16; ++w1)
        og[(w1 * 16 + w0) * 128 + c] = Ur[w1] * inv;
    }
  }
}

extern "C" void kernel_launch(void* const* d_in, const int* in_sizes, int n_in,
                              void* d_out, int out_size, void* d_ws, size_t ws_size,
                              hipStream_t stream) {
  const float* x = (const float*)d_in[0];
  const float* w = (const float*)d_in[1];
  const float* b = (const float*)d_in[2];
  float* out = (float*)d_out;
  float2* wsW = (float2*)d_ws;
  float2* wsB = wsW + 32 * 32 * 65;   // 66560 float2 each (532,480 B)

  hipLaunchKernelGGL(k0_wft_and_fill, dim3(64 + NF0), dim3(TPK), 0, stream,
                     w, b, wsW, wsB, out);
  hipLaunchKernelGGL(fourier_main, dim3(NACT), dim3(TPA), 0, stream,
                     x, wsW, wsB, out);
}